// Round 2
// baseline (1584.956 us; speedup 1.0000x reference)
//
#include <hip/hip_runtime.h>

#define MAXNB 2048
#define ACC_STRIDE 516    // 512 + 4: rows 4 banks apart -> conflict-free b128
#define XROW_STRIDE 68    // 64 + 4

#define FMA4(sumv, a, w0, w1, w2, w3)                          \
    sumv.x += a.x * w0.x + a.y * w1.x + a.z * w2.x + a.w * w3.x; \
    sumv.y += a.x * w0.y + a.y * w1.y + a.z * w2.y + a.w * w3.y; \
    sumv.z += a.x * w0.z + a.y * w1.z + a.z * w2.z + a.w * w3.z; \
    sumv.w += a.x * w0.w + a.y * w1.w + a.z * w2.w + a.w * w3.w;

__global__ __launch_bounds__(512) void hist_kernel(
    const int* __restrict__ dst, int* __restrict__ hist, int n_edges)
{
    __shared__ int lh[MAXNB];
    const int t = threadIdx.x;
    for (int i = t; i < MAXNB; i += 512) lh[i] = 0;
    __syncthreads();
    for (int e = blockIdx.x * 512 + t; e < n_edges; e += gridDim.x * 512)
        atomicAdd(&lh[dst[e] >> 6], 1);
    __syncthreads();
    for (int i = t; i < MAXNB; i += 512) {
        int c = lh[i];
        if (c) atomicAdd(&hist[i], c);
    }
}

__global__ __launch_bounds__(64) void scan_kernel(
    const int* __restrict__ hist, int* __restrict__ bstart, int nb)
{
    const int lane = threadIdx.x;
    int running = 0;
    for (int base = 0; base < nb; base += 64) {
        int i = base + lane;
        int o = (i < nb) ? hist[i] : 0;
        int v = o;
#pragma unroll
        for (int off = 1; off < 64; off <<= 1) {
            int u = __shfl_up(v, off);
            if (lane >= off) v += u;
        }
        if (i < nb) bstart[i] = running + v - o;  // exclusive
        running += __shfl(v, 63);
    }
}

__global__ __launch_bounds__(512) void scatter_kernel(
    const int* __restrict__ src, const int* __restrict__ dst,
    const int* __restrict__ et, const int* __restrict__ bstart,
    int* __restrict__ cursor, unsigned int* __restrict__ recs,
    int n_edges, int chunk)
{
    __shared__ int lh[MAXNB];
    __shared__ int lbase[MAXNB];
    const int t = threadIdx.x;
    const int e0 = blockIdx.x * chunk;
    const int e1 = min(n_edges, e0 + chunk);
    for (int i = t; i < MAXNB; i += 512) lh[i] = 0;
    __syncthreads();
    for (int e = e0 + t; e < e1; e += 512) atomicAdd(&lh[dst[e] >> 6], 1);
    __syncthreads();
    for (int i = t; i < MAXNB; i += 512) {
        int c = lh[i];
        lbase[i] = c ? atomicAdd(&cursor[i], c) : 0;  // guard avoids OOB for i>=NB (c==0)
        lh[i] = 0;
    }
    __syncthreads();
    for (int e = e0 + t; e < e1; e += 512) {
        int d = dst[e];
        int bkt = d >> 6;
        int rank = atomicAdd(&lh[bkt], 1);
        int pos = bstart[bkt] + lbase[bkt] + rank;
        recs[pos] = (unsigned)src[e] | ((unsigned)et[e] << 17)
                  | ((unsigned)(d & 63) << 20);
    }
}

// One block per bucket of 64 dst-nodes. acc[64][8][64] lives in LDS.
template <int DOUT, int RELU>
__global__ __launch_bounds__(512, 1) void rgcn_bucket_kernel(
    const float* __restrict__ xin,       // (N, 64)
    const unsigned int* __restrict__ recs,
    const int* __restrict__ bstart,
    const int* __restrict__ hist,
    const float* __restrict__ W,         // (8,64,DOUT) == (512, DOUT)
    const float* __restrict__ root,      // (64, DOUT)
    const float* __restrict__ bias,      // (DOUT)
    float* __restrict__ out,             // (N, DOUT)
    int n_nodes)
{
    __shared__ float acc_s[64 * ACC_STRIDE];   // 132.0 KB
    __shared__ float xrow_s[64 * XROW_STRIDE]; // 17.4 KB
    __shared__ int cnt_s[512];
    __shared__ float scale_s[512];

    const int t = threadIdx.x;
    const int node0 = blockIdx.x * 64;
    const float4* x4 = (const float4*)xin;

    for (int i = t; i < 64 * ACC_STRIDE; i += 512) acc_s[i] = 0.0f;
    cnt_s[t] = 0;
    for (int i = t; i < 1024; i += 512) {  // stage bucket's own x rows
        int row = i >> 4, qq = i & 15;
        int node = node0 + row;
        float4 v{0.f, 0.f, 0.f, 0.f};
        if (node < n_nodes) v = x4[(size_t)node * 16 + qq];
        *(float4*)&xrow_s[row * XROW_STRIDE + qq * 4] = v;
    }
    __syncthreads();

    // ---- edge aggregation phase ----
    const int start = bstart[blockIdx.x];
    const int len = hist[blockIdx.x];
    const int g = t >> 4;        // 32 groups of 16 lanes
    const int q = t & 15;
    const int q4 = q * 4;

    auto edge_add = [&](unsigned r, float4 v) {
        int dl = (r >> 20) & 63;
        int rel = (r >> 17) & 7;
        float* p = &acc_s[dl * ACC_STRIDE + rel * 64 + q4];
        atomicAdd(p + 0, v.x);
        atomicAdd(p + 1, v.y);
        atomicAdd(p + 2, v.z);
        atomicAdd(p + 3, v.w);
        if (q == 0) atomicAdd(&cnt_s[dl * 8 + rel], 1);
    };

    int i = g;
    for (; i + 96 < len; i += 128) {
        unsigned r0 = recs[start + i];
        unsigned r1 = recs[start + i + 32];
        unsigned r2 = recs[start + i + 64];
        unsigned r3 = recs[start + i + 96];
        float4 v0 = x4[(size_t)(r0 & 0x1FFFF) * 16 + q];
        float4 v1 = x4[(size_t)(r1 & 0x1FFFF) * 16 + q];
        float4 v2 = x4[(size_t)(r2 & 0x1FFFF) * 16 + q];
        float4 v3 = x4[(size_t)(r3 & 0x1FFFF) * 16 + q];
        edge_add(r0, v0);
        edge_add(r1, v1);
        edge_add(r2, v2);
        edge_add(r3, v3);
    }
    for (; i < len; i += 32) {
        unsigned r = recs[start + i];
        float4 v = x4[(size_t)(r & 0x1FFFF) * 16 + q];
        edge_add(r, v);
    }
    __syncthreads();

    // ---- scale by 1/max(cnt,1), in place ----
    {
        float c = (float)cnt_s[t];
        scale_s[t] = 1.0f / fmaxf(c, 1.0f);
    }
    __syncthreads();
    for (int idx = t; idx < 64 * 512; idx += 512) {
        int row = idx >> 9, kk = idx & 511;
        acc_s[row * ACC_STRIDE + kk] *= scale_s[(row << 3) | (kk >> 6)];
    }
    __syncthreads();

    // ---- dense transform: out = [x | accS] @ [root; W] + b ----
    constexpr int JT = DOUT / 4;   // threads along j
    constexpr int MT = 512 / JT;   // thread groups along nodes
    constexpr int NPT = 64 / MT;   // nodes per thread
    const int jt = t % JT;
    const int mtg = t / JT;

    float4 sum[NPT];
    {
        float4 b4 = *(const float4*)&bias[jt * 4];
#pragma unroll
        for (int m = 0; m < NPT; ++m) sum[m] = b4;
    }

#pragma unroll 2
    for (int kk = 0; kk < 64; kk += 4) {
        float4 w0 = *(const float4*)&root[(kk + 0) * DOUT + jt * 4];
        float4 w1 = *(const float4*)&root[(kk + 1) * DOUT + jt * 4];
        float4 w2 = *(const float4*)&root[(kk + 2) * DOUT + jt * 4];
        float4 w3 = *(const float4*)&root[(kk + 3) * DOUT + jt * 4];
#pragma unroll
        for (int m = 0; m < NPT; ++m) {
            float4 a = *(const float4*)&xrow_s[(mtg * NPT + m) * XROW_STRIDE + kk];
            FMA4(sum[m], a, w0, w1, w2, w3);
        }
    }

#pragma unroll 2
    for (int kk = 0; kk < 512; kk += 4) {
        float4 w0 = *(const float4*)&W[(kk + 0) * DOUT + jt * 4];
        float4 w1 = *(const float4*)&W[(kk + 1) * DOUT + jt * 4];
        float4 w2 = *(const float4*)&W[(kk + 2) * DOUT + jt * 4];
        float4 w3 = *(const float4*)&W[(kk + 3) * DOUT + jt * 4];
#pragma unroll
        for (int m = 0; m < NPT; ++m) {
            float4 a = *(const float4*)&acc_s[(mtg * NPT + m) * ACC_STRIDE + kk];
            FMA4(sum[m], a, w0, w1, w2, w3);
        }
    }

#pragma unroll
    for (int m = 0; m < NPT; ++m) {
        int node = node0 + mtg * NPT + m;
        if (node < n_nodes) {
            float4 v = sum[m];
            if (RELU) {
                v.x = fmaxf(v.x, 0.f);
                v.y = fmaxf(v.y, 0.f);
                v.z = fmaxf(v.z, 0.f);
                v.w = fmaxf(v.w, 0.f);
            }
            *(float4*)&out[(size_t)node * DOUT + jt * 4] = v;
        }
    }
}

extern "C" void kernel_launch(void* const* d_in, const int* in_sizes, int n_in,
                              void* d_out, int out_size, void* d_ws, size_t ws_size,
                              hipStream_t stream) {
    const float* x     = (const float*)d_in[0];
    const float* W1    = (const float*)d_in[1];
    const float* root1 = (const float*)d_in[2];
    const float* b1    = (const float*)d_in[3];
    const float* W2    = (const float*)d_in[4];
    const float* root2 = (const float*)d_in[5];
    const float* b2    = (const float*)d_in[6];
    const int*   src   = (const int*)d_in[7];
    const int*   dst   = (const int*)d_in[8];
    const int*   et    = (const int*)d_in[9];

    const int N = in_sizes[0] / 64;
    const int E = in_sizes[7];
    const int NB = (N + 63) / 64;  // 1563 for N=100000; must be <= MAXNB

    // ws layout: recs (E u32) | hist (NB) | bstart (NB) | cursor (NB) | pad | h (N*64 f32)
    unsigned int* recs = (unsigned int*)d_ws;
    int* hist = (int*)(recs + E);
    int* bstart = hist + NB;
    int* cursor = bstart + NB;
    size_t off = (size_t)E + 3 * (size_t)NB;
    off = (off + 3) & ~(size_t)3;  // 16 B align for float4 access to h
    float* h = (float*)d_ws + off;

    hipMemsetAsync(hist, 0, (size_t)3 * NB * sizeof(int), stream);  // hist|bstart|cursor
    hist_kernel<<<192, 512, 0, stream>>>(dst, hist, E);
    scan_kernel<<<1, 64, 0, stream>>>(hist, bstart, NB);
    const int chunk = (E + 191) / 192;
    scatter_kernel<<<192, 512, 0, stream>>>(src, dst, et, bstart, cursor, recs, E, chunk);

    rgcn_bucket_kernel<64, 1><<<NB, 512, 0, stream>>>(
        x, recs, bstart, hist, W1, root1, b1, h, N);
    rgcn_bucket_kernel<32, 0><<<NB, 512, 0, stream>>>(
        h, recs, bstart, hist, W2, root2, b2, (float*)d_out, N);
}

// Round 3
// 1216.701 us; speedup vs baseline: 1.3027x; 1.3027x over previous
//
#include <hip/hip_runtime.h>

#define MAXNB 2048
#define ACC_STRIDE 516    // 512 + 4 floats: rows 4 banks apart -> 2-way (free) on b128
#define WT_STRIDE 72      // shorts per j-row of W chunk (64 k + 8 pad)

typedef __attribute__((ext_vector_type(8))) short short8;
typedef __attribute__((ext_vector_type(4))) float f32x4;

__global__ __launch_bounds__(512) void hist_kernel(
    const int* __restrict__ dst, int* __restrict__ hist, int n_edges)
{
    __shared__ int lh[MAXNB];
    const int t = threadIdx.x;
    for (int i = t; i < MAXNB; i += 512) lh[i] = 0;
    __syncthreads();
    for (int e = blockIdx.x * 512 + t; e < n_edges; e += gridDim.x * 512)
        atomicAdd(&lh[dst[e] >> 6], 1);
    __syncthreads();
    for (int i = t; i < MAXNB; i += 512) {
        int c = lh[i];
        if (c) atomicAdd(&hist[i], c);
    }
}

__global__ __launch_bounds__(64) void scan_kernel(
    const int* __restrict__ hist, int* __restrict__ bstart, int nb)
{
    const int lane = threadIdx.x;
    int running = 0;
    for (int base = 0; base < nb; base += 64) {
        int i = base + lane;
        int o = (i < nb) ? hist[i] : 0;
        int v = o;
#pragma unroll
        for (int off = 1; off < 64; off <<= 1) {
            int u = __shfl_up(v, off);
            if (lane >= off) v += u;
        }
        if (i < nb) bstart[i] = running + v - o;  // exclusive
        running += __shfl(v, 63);
    }
}

__global__ __launch_bounds__(512) void scatter_kernel(
    const int* __restrict__ src, const int* __restrict__ dst,
    const int* __restrict__ et, const int* __restrict__ bstart,
    int* __restrict__ cursor, unsigned int* __restrict__ recs,
    int n_edges, int chunk)
{
    __shared__ int lh[MAXNB];
    __shared__ int lbase[MAXNB];
    const int t = threadIdx.x;
    const int e0 = blockIdx.x * chunk;
    const int e1 = min(n_edges, e0 + chunk);
    for (int i = t; i < MAXNB; i += 512) lh[i] = 0;
    __syncthreads();
    for (int e = e0 + t; e < e1; e += 512) atomicAdd(&lh[dst[e] >> 6], 1);
    __syncthreads();
    for (int i = t; i < MAXNB; i += 512) {
        int c = lh[i];
        lbase[i] = c ? atomicAdd(&cursor[i], c) : 0;
        lh[i] = 0;
    }
    __syncthreads();
    for (int e = e0 + t; e < e1; e += 512) {
        int d = dst[e];
        int bkt = d >> 6;
        int rank = atomicAdd(&lh[bkt], 1);
        int pos = bstart[bkt] + lbase[bkt] + rank;
        recs[pos] = (unsigned)src[e] | ((unsigned)et[e] << 17)
                  | ((unsigned)(d & 63) << 20);
    }
}

// One block (1024 threads = 16 waves) per bucket of 64 dst nodes.
// Phase 1: LDS fp32 atomic aggregation of x[src] per (dst, rel).
// Phase 2: MFMA bf16 (hi/lo split) GEMM: out = [x | means] @ [root; W] + b.
template <int DOUT, int RELU>
__global__ __launch_bounds__(1024) void rgcn_bucket_kernel(
    const float* __restrict__ xin,       // (N, 64)
    const unsigned int* __restrict__ recs,
    const int* __restrict__ bstart,
    const int* __restrict__ hist,
    const float* __restrict__ W,         // (8, 64, DOUT)
    const float* __restrict__ root,      // (64, DOUT)
    const float* __restrict__ bias,      // (DOUT)
    float* __restrict__ out,             // (N, DOUT)
    int n_nodes)
{
    __shared__ float acc_s[64 * ACC_STRIDE];   // 132096 B
    __shared__ short wt_hi[64 * WT_STRIDE];    // 9216 B
    __shared__ short wt_lo[64 * WT_STRIDE];    // 9216 B
    __shared__ int   cnt_s[512];               // 2048 B
    __shared__ float scale_s[512];             // 2048 B

    const int t = threadIdx.x;
    const int node0 = blockIdx.x * 64;
    const float4* x4 = (const float4*)xin;

    // ---- W chunk-0 (root) register prefetch: issue ASAP, consumed after phase 1
    constexpr int WELEMS = (64 * DOUT) / 1024;  // 4 (DOUT=64) or 2 (DOUT=32)
    float wreg[WELEMS];
#pragma unroll
    for (int i = 0; i < WELEMS; ++i) wreg[i] = root[t + i * 1024];

    // ---- init LDS ----
    for (int i = t; i < 64 * ACC_STRIDE; i += 1024) acc_s[i] = 0.0f;
    if (t < 512) cnt_s[t] = 0;
    __syncthreads();

    // ---- phase 1: edge aggregation (64 groups of 16 lanes) ----
    const int start = bstart[blockIdx.x];
    const int len = hist[blockIdx.x];
    {
        const int g = t >> 4;
        const int q = t & 15;
        const int q4 = q * 4;
        auto edge_add = [&](unsigned r, float4 v) {
            int dl = (r >> 20) & 63;
            int rel = (r >> 17) & 7;
            float* p = &acc_s[dl * ACC_STRIDE + rel * 64 + q4];
            atomicAdd(p + 0, v.x);
            atomicAdd(p + 1, v.y);
            atomicAdd(p + 2, v.z);
            atomicAdd(p + 3, v.w);
            if (q == 0) atomicAdd(&cnt_s[dl * 8 + rel], 1);
        };
        int i = g;
        for (; i + 192 < len; i += 256) {
            unsigned r0 = recs[start + i];
            unsigned r1 = recs[start + i + 64];
            unsigned r2 = recs[start + i + 128];
            unsigned r3 = recs[start + i + 192];
            float4 v0 = x4[(size_t)(r0 & 0x1FFFF) * 16 + q];
            float4 v1 = x4[(size_t)(r1 & 0x1FFFF) * 16 + q];
            float4 v2 = x4[(size_t)(r2 & 0x1FFFF) * 16 + q];
            float4 v3 = x4[(size_t)(r3 & 0x1FFFF) * 16 + q];
            edge_add(r0, v0);
            edge_add(r1, v1);
            edge_add(r2, v2);
            edge_add(r3, v3);
        }
        for (; i < len; i += 64) {
            unsigned r = recs[start + i];
            float4 v = x4[(size_t)(r & 0x1FFFF) * 16 + q];
            edge_add(r, v);
        }
    }
    __syncthreads();

    // ---- per-(node,rel) reciprocal counts ----
    if (t < 512) scale_s[t] = 1.0f / fmaxf((float)cnt_s[t], 1.0f);
    __syncthreads();

    // ---- phase 2: MFMA GEMM over 9 chunks of K=64 (root, then 8 relations) ----
    const int w = t >> 6;
    const int lane = t & 63;
    const int quad = lane >> 4;
    const int l16 = lane & 15;
    constexpr int NTILES = 4 * (DOUT / 16);  // 16 or 8
    const int mt = w & 3;
    const int nt = w >> 2;
    const int m = mt * 16 + l16;   // A row (node within bucket)
    const int j = nt * 16 + l16;   // B col (output feature)
    f32x4 d = {0.f, 0.f, 0.f, 0.f};

    for (int c = 0; c < 9; ++c) {
        // write prefetched chunk c to LDS as bf16 hi/lo
#pragma unroll
        for (int i = 0; i < WELEMS; ++i) {
            int e = t + i * 1024;
            int jj = e % DOUT;
            int kk = e / DOUT;
            float f = wreg[i];
            unsigned u = __float_as_uint(f);
            wt_hi[jj * WT_STRIDE + kk] = (short)(u >> 16);
            float fl = f - __uint_as_float(u & 0xFFFF0000u);
            wt_lo[jj * WT_STRIDE + kk] = (short)(__float_as_uint(fl) >> 16);
        }
        __syncthreads();
        // prefetch chunk c+1
        if (c + 1 < 9) {
            const float* wsrc = W + (size_t)c * 64 * DOUT;
#pragma unroll
            for (int i = 0; i < WELEMS; ++i) wreg[i] = wsrc[t + i * 1024];
        }
        // compute chunk c
        if (w < NTILES) {
            float sc = (c > 0) ? scale_s[m * 8 + (c - 1)] : 1.0f;
#pragma unroll
            for (int ks = 0; ks < 2; ++ks) {
                const int ko = ks * 32 + quad * 8;
                short8 bh = *(const short8*)&wt_hi[j * WT_STRIDE + ko];
                short8 bl = *(const short8*)&wt_lo[j * WT_STRIDE + ko];
                float a[8];
                if (c == 0) {
                    const int node = node0 + m;
                    if (node < n_nodes) {
                        const float* xr = xin + (size_t)node * 64 + ko;
#pragma unroll
                        for (int i2 = 0; i2 < 8; ++i2) a[i2] = xr[i2];
                    } else {
#pragma unroll
                        for (int i2 = 0; i2 < 8; ++i2) a[i2] = 0.0f;
                    }
                } else {
                    const float* ar = &acc_s[m * ACC_STRIDE + (c - 1) * 64 + ko];
#pragma unroll
                    for (int i2 = 0; i2 < 8; ++i2) a[i2] = ar[i2] * sc;
                }
                short8 ah, al;
#pragma unroll
                for (int i2 = 0; i2 < 8; ++i2) {
                    float av = a[i2];
                    unsigned u = __float_as_uint(av);
                    ah[i2] = (short)(u >> 16);
                    float fl = av - __uint_as_float(u & 0xFFFF0000u);
                    al[i2] = (short)(__float_as_uint(fl) >> 16);
                }
                d = __builtin_amdgcn_mfma_f32_16x16x32_bf16(ah, bh, d, 0, 0, 0);
                d = __builtin_amdgcn_mfma_f32_16x16x32_bf16(ah, bl, d, 0, 0, 0);
                d = __builtin_amdgcn_mfma_f32_16x16x32_bf16(al, bh, d, 0, 0, 0);
            }
        }
        __syncthreads();
    }

    // ---- epilogue: C/D layout col=lane&15 (=j), row=quad*4+reg (=m) ----
    if (w < NTILES) {
        const float bj = bias[j];
#pragma unroll
        for (int r = 0; r < 4; ++r) {
            const int mm = mt * 16 + quad * 4 + r;
            const int node = node0 + mm;
            if (node < n_nodes) {
                float v = d[r] + bj;
                if (RELU) v = fmaxf(v, 0.0f);
                out[(size_t)node * DOUT + j] = v;
            }
        }
    }
}

extern "C" void kernel_launch(void* const* d_in, const int* in_sizes, int n_in,
                              void* d_out, int out_size, void* d_ws, size_t ws_size,
                              hipStream_t stream) {
    const float* x     = (const float*)d_in[0];
    const float* W1    = (const float*)d_in[1];
    const float* root1 = (const float*)d_in[2];
    const float* b1    = (const float*)d_in[3];
    const float* W2    = (const float*)d_in[4];
    const float* root2 = (const float*)d_in[5];
    const float* b2    = (const float*)d_in[6];
    const int*   src   = (const int*)d_in[7];
    const int*   dst   = (const int*)d_in[8];
    const int*   et    = (const int*)d_in[9];

    const int N = in_sizes[0] / 64;
    const int E = in_sizes[7];
    const int NB = (N + 63) / 64;  // 1563 for N=100000; must be <= MAXNB

    // ws layout: recs (E u32) | hist | bstart | cursor | pad | h (N*64 f32)
    unsigned int* recs = (unsigned int*)d_ws;
    int* hist = (int*)(recs + E);
    int* bstart = hist + NB;
    int* cursor = bstart + NB;
    size_t off = (size_t)E + 3 * (size_t)NB;
    off = (off + 3) & ~(size_t)3;
    float* h = (float*)d_ws + off;

    hipMemsetAsync(hist, 0, (size_t)3 * NB * sizeof(int), stream);
    hist_kernel<<<192, 512, 0, stream>>>(dst, hist, E);
    scan_kernel<<<1, 64, 0, stream>>>(hist, bstart, NB);
    const int chunk = (E + 191) / 192;
    scatter_kernel<<<192, 512, 0, stream>>>(src, dst, et, bstart, cursor, recs, E, chunk);

    rgcn_bucket_kernel<64, 1><<<NB, 1024, 0, stream>>>(
        x, recs, bstart, hist, W1, root1, b1, h, N);
    rgcn_bucket_kernel<32, 0><<<NB, 1024, 0, stream>>>(
        h, recs, bstart, hist, W2, root2, b2, (float*)d_out, N);
}